// Round 9
// baseline (135.652 us; speedup 1.0000x reference)
//
#include <hip/hip_runtime.h>

// Simplex projection along last dim (n = 12288), rows = 4096, fp32.
// wp = max(x - tau, 0), wc = x - wp, tau solves sum(max(x-tau,0)) = Z.
//
// SINGLE KERNEL, SINGLE PASS, WRITE-THEN-FIX, ZERO BARRIERS, ~32 VGPR:
//   stream loop (per f32x4): load x -> store wp = 0 -> store wc = x
//   (both provisional stores are exact for every element with x <= tau, i.e.
//   all but ~5 of 12288), accumulate sAll, ballot-append the ~280 elements
//   > 2.0 (value+index) into a per-wave LDS list -- wave-uniform SGPR counter
//   + popc offsets, no atomics, the append branch is wave-uniform and almost
//   always not taken.
//   Then: bootstrap-validate t in {2,3} (g(t)=S_t-t*C_t >= Z  <=>  t <= tau*),
//   Michelot on the LDS list (~4 iters, shuffles only), s_waitcnt vmcnt(0)
//   (own provisional stores landed), scatter-fix the true actives:
//   wp[idx] = a - tau, wc[idx] = tau.  (Ordering pattern validated in R7/R8.)
//   Fallback (invalid bootstrap / LDS overflow): re-read row, full Michelot,
//   full rewrite. Never taken for N(0,1) rows.
//
// Why this shape: 576 MB irreducible traffic in ONE kernel; ~32 VGPR => full
// occupancy, so the ~0.5us per-row solve tail hides under 15+ other resident
// waves' streams (R6's 192-VGPR row residency allowed only 2 waves/SIMD and
// left ~20us of VMEM-idle). Plain loads/stores (the 6.9 TB/s fill and 6.3 TB/s
// copy references use plain accesses; NT variants measured 4.9-5.0 TB/s here).
//
// Michelot from subset start: if A0 = {x > t} with t <= tau*, every iterate
// tau_k in [t, tau*], active sets stay within A0, counts strictly shrink to
// the fixed point; count-stable <=> exact. Validity g(t) >= Z <=> tau0 >= t.

constexpr int   N_COLS = 12288;
constexpr int   WAVE   = 64;
constexpr int   WPB    = 4;                     // waves (rows) per block
constexpr int   BLOCK  = WAVE * WPB;            // 256
constexpr int   V4     = N_COLS / (WAVE * 4);   // 48 f32x4 per lane
constexpr float Z_LVL  = 1.0f;
constexpr int   CAP    = 512;                   // per-wave list cap (mean 280, sd 17)
constexpr float T2     = 2.0f;
constexpr float T3     = 3.0f;

typedef float f32x4 __attribute__((ext_vector_type(4)));

__device__ __forceinline__ float wsum(float v) {
#pragma unroll
  for (int off = 32; off >= 1; off >>= 1) v += __shfl_xor(v, off, 64);
  return v;
}
__device__ __forceinline__ int wsumi(int v) {
#pragma unroll
  for (int off = 32; off >= 1; off >>= 1) v += __shfl_xor(v, off, 64);
  return v;
}

__global__ __launch_bounds__(BLOCK) void simplex_stream(
    const float* __restrict__ x, float* __restrict__ wp, float* __restrict__ wc,
    int rows) {

  const int lane = threadIdx.x & 63;
  const int wv   = threadIdx.x >> 6;
  const int row  = blockIdx.x * WPB + wv;
  if (row >= rows) return;

  const size_t base = (size_t)row * N_COLS;
  const f32x4* __restrict__ xin = reinterpret_cast<const f32x4*>(x + base);
  f32x4* __restrict__ wpo = reinterpret_cast<f32x4*>(wp + base);
  f32x4* __restrict__ wco = reinterpret_cast<f32x4*>(wc + base);

  __shared__ float s_act[WPB][CAP];
  __shared__ int   s_idx[WPB][CAP];

  const unsigned long long lt_mask = (lane == 0) ? 0ull : (~0ull >> (64 - lane));
  const f32x4 zero4 = {0.f, 0.f, 0.f, 0.f};

  float sAll = 0.f;
  int   n    = 0;      // wave-uniform list length (SGPR)
  bool  ovf  = false;

  // ---- stream: load -> wp=0 -> wc=x -> sum + ballot-append (>2.0) ----
#pragma unroll 8
  for (int k = 0; k < V4; ++k) {
    f32x4 t = xin[lane + k * WAVE];
    wpo[lane + k * WAVE] = zero4;          // no dependency: issues immediately
    wco[lane + k * WAVE] = t;              // provisional wc = x
#pragma unroll
    for (int j = 0; j < 4; ++j) {
      float e = t[j];
      sAll += e;
      unsigned long long m = __ballot(e > T2);
      if (m) {                             // wave-uniform branch, rarely taken
        int c = (int)__popcll(m);
        if (n + c <= CAP) {
          if (e > T2) {
            int o = n + (int)__popcll(m & lt_mask);
            s_act[wv][o] = e;
            s_idx[wv][o] = 4 * (lane + k * WAVE) + j;
          }
        } else {
          ovf = true;
        }
        n += c;
      }
    }
  }
  sAll = wsum(sAll);

  bool ok = !ovf && (n > 0);
  float tau = 0.f;
  int   prev = 0;

  if (ok) {
    asm volatile("s_waitcnt lgkmcnt(0)" ::: "memory");  // list visible in-wave
    // ---- stats from the compacted list ----
    float s2 = 0.f, s3 = 0.f;
    int   c3 = 0;
    for (int i = lane; i < n; i += WAVE) {
      float a = s_act[wv][i];
      s2 += a;
      bool g3 = a > T3;
      s3 += g3 ? a : 0.f;
      c3 += g3 ? 1 : 0;
    }
    s2 = wsum(s2);  s3 = wsum(s3);  c3 = wsumi(c3);
    const int c2 = n;

    if (c3 > 0 && (s3 - 3.f * (float)c3) >= Z_LVL + 0.01f) {
      tau = (s3 - Z_LVL) / (float)c3;  prev = c3;           // tau >= 3
    } else if ((s2 - 2.f * (float)c2) >= Z_LVL + 0.01f) {
      tau = (s2 - Z_LVL) / (float)c2;  prev = c2;           // tau >= 2
    } else {
      ok = false;                                           // tau* < 2: fallback
    }

    if (ok) {
      // ---- Michelot on the list (active sets stay within {x>2}) ----
      for (int it = 0; it < CAP + 2; ++it) {
        float ps = 0.f; int pc = 0;
        for (int i = lane; i < n; i += WAVE) {
          float a = s_act[wv][i];
          bool  g = a > tau;
          ps += g ? a : 0.f;
          pc += g ? 1 : 0;
        }
        ps = wsum(ps);  pc = wsumi(pc);
        tau = (ps - Z_LVL) / (float)pc;
        if (pc == prev) break;                              // stable -> exact
        prev = pc;
      }
      // ---- scatter-fix true actives (after provisional stores land) ----
      asm volatile("s_waitcnt vmcnt(0)" ::: "memory");
      float* __restrict__ wps = wp + base;
      float* __restrict__ wcs = wc + base;
      for (int i = lane; i < n; i += WAVE) {
        float a = s_act[wv][i];
        if (a > tau) {
          int idx = s_idx[wv][i];
          wps[idx] = a - tau;                               // over wp = 0
          wcs[idx] = tau;                                   // over wc = x
        }
      }
      return;
    }
  }

  // ---- fallback (adversarial data only): full Michelot + full rewrite ----
  {
    tau = (sAll - Z_LVL) / (float)N_COLS;
    prev = N_COLS;
    for (int it = 0; it < 100; ++it) {
      float ps = 0.f; int pc = 0;
      for (int k = 0; k < V4; ++k) {
        f32x4 t = xin[lane + k * WAVE];
#pragma unroll
        for (int j = 0; j < 4; ++j) {
          bool g = t[j] > tau;
          ps += g ? t[j] : 0.f;
          pc += g ? 1 : 0;
        }
      }
      ps = wsum(ps);  pc = wsumi(pc);
      tau = (ps - Z_LVL) / (float)pc;
      if (pc == prev) break;
      prev = pc;
    }
    asm volatile("s_waitcnt vmcnt(0)" ::: "memory");
    for (int k = 0; k < V4; ++k) {
      f32x4 t = xin[lane + k * WAVE];
      f32x4 pv, cv;
#pragma unroll
      for (int j = 0; j < 4; ++j) {
        pv[j] = fmaxf(t[j] - tau, 0.f);
        cv[j] = t[j] - pv[j];
      }
      wpo[lane + k * WAVE] = pv;
      wco[lane + k * WAVE] = cv;
    }
  }
}

extern "C" void kernel_launch(void* const* d_in, const int* in_sizes, int n_in,
                              void* d_out, int out_size, void* d_ws, size_t ws_size,
                              hipStream_t stream) {
  const float* x = (const float*)d_in[0];
  const int rows = in_sizes[0] / N_COLS;

  float* wp = (float*)d_out;
  float* wc = wp + (size_t)rows * N_COLS;

  const int nblk = (rows + WPB - 1) / WPB;
  simplex_stream<<<nblk, BLOCK, 0, stream>>>(x, wp, wc, rows);
}

// Round 10
// 110.626 us; speedup vs baseline: 1.2262x; 1.2262x over previous
//
#include <hip/hip_runtime.h>

// Simplex projection along last dim (n = 12288), rows = 4096, fp32.
// wp = max(x - tau, 0), wc = x - wp, tau solves sum(max(x-tau,0)) = Z.
//
// FUSED TWO-PHASE, ONE WAVE PER ROW, ZERO BARRIERS, <=2 HBM STREAMS/PHASE:
//   phase 1 (pure read): stream the row with PLAIN loads (allocates x in the
//     256MB L3; x = 192MB fits), accumulate sAll and ballot-append the ~280
//     elements > 2.0 (value only) to a per-wave LDS list. No stores, no
//     register row residency -> ~40 VGPR, full occupancy.
//   solve: bootstrap-validate t in {2,3} (g(t)=S_t-t*C_t >= Z  <=>  t <= tau*),
//     Michelot on the LDS list (~4 iters, ballot/shuffle only). Fallback to
//     full-row Michelot via cached re-reads if invalid (never for N(0,1)).
//   phase 2 (read + 2 writes): re-read the row (L2/L3-hot, plain loads),
//     compute wp/wc, NT-store both (NT stores don't allocate -> x stays L3
//     resident for other rows).
// vs R5's two-kernel version: no inter-kernel global sync (early rows write
// while late rows read -> streams mix all kernel long), no tau roundtrip, no
// launch gap. vs R9: the wp=0 stream is gone from the hot loop (3->2 streams).
//
// Michelot from subset start: if A0 = {x > t} with t <= tau*, every iterate
// tau_k in [t, tau*], active sets stay within A0, counts shrink to the fixed
// point; count-stable <=> exact. Validity g(t) >= Z <=> tau0 >= t.

constexpr int   N_COLS = 12288;
constexpr int   WAVE   = 64;
constexpr int   WPB    = 4;                     // waves (rows) per block
constexpr int   BLOCK  = WAVE * WPB;            // 256
constexpr int   V4     = N_COLS / (WAVE * 4);   // 48 f32x4 per lane
constexpr float Z_LVL  = 1.0f;
constexpr int   CAP    = 512;                   // per-wave list cap (mean 280, sd 17)
constexpr float T2     = 2.0f;
constexpr float T3     = 3.0f;

typedef float f32x4 __attribute__((ext_vector_type(4)));

__device__ __forceinline__ float wsum(float v) {
#pragma unroll
  for (int off = 32; off >= 1; off >>= 1) v += __shfl_xor(v, off, 64);
  return v;
}
__device__ __forceinline__ int wsumi(int v) {
#pragma unroll
  for (int off = 32; off >= 1; off >>= 1) v += __shfl_xor(v, off, 64);
  return v;
}

__global__ __launch_bounds__(BLOCK) void simplex_fused2(
    const float* __restrict__ x, float* __restrict__ wp, float* __restrict__ wc,
    int rows) {

  const int lane = threadIdx.x & 63;
  const int wv   = threadIdx.x >> 6;
  const int row  = blockIdx.x * WPB + wv;
  if (row >= rows) return;

  const size_t base = (size_t)row * N_COLS;
  const f32x4* __restrict__ xin = reinterpret_cast<const f32x4*>(x + base);

  __shared__ float s_act[WPB][CAP];

  const unsigned long long lt_mask = (lane == 0) ? 0ull : (~0ull >> (64 - lane));

  // ---- phase 1: pure streaming read + stats + ballot-append (>2.0) ----
  float sAll = 0.f;
  int   n    = 0;      // wave-uniform list length (SGPR)
  bool  ovf  = false;

#pragma unroll 8
  for (int k = 0; k < V4; ++k) {
    f32x4 t = xin[lane + k * WAVE];        // plain load: allocate in L3
#pragma unroll
    for (int j = 0; j < 4; ++j) {
      float e = t[j];
      sAll += e;
      unsigned long long m = __ballot(e > T2);
      if (m) {                             // wave-uniform branch, rarely taken
        int c = (int)__popcll(m);
        if (n + c <= CAP) {
          if (e > T2) {
            s_act[wv][n + (int)__popcll(m & lt_mask)] = e;
          }
        } else {
          ovf = true;
        }
        n += c;
      }
    }
  }
  sAll = wsum(sAll);

  // ---- solve tau ----
  float tau = 0.f;
  int   prev = 0;
  bool  ok = !ovf && (n > 0);

  if (ok) {
    asm volatile("s_waitcnt lgkmcnt(0)" ::: "memory");  // list visible in-wave
    float s2 = 0.f, s3 = 0.f;
    int   c3 = 0;
    for (int i = lane; i < n; i += WAVE) {
      float a = s_act[wv][i];
      s2 += a;
      bool g3 = a > T3;
      s3 += g3 ? a : 0.f;
      c3 += g3 ? 1 : 0;
    }
    s2 = wsum(s2);  s3 = wsum(s3);  c3 = wsumi(c3);
    const int c2 = n;

    if (c3 > 0 && (s3 - 3.f * (float)c3) >= Z_LVL + 0.01f) {
      tau = (s3 - Z_LVL) / (float)c3;  prev = c3;           // tau >= 3
    } else if ((s2 - 2.f * (float)c2) >= Z_LVL + 0.01f) {
      tau = (s2 - Z_LVL) / (float)c2;  prev = c2;           // tau >= 2
    } else {
      ok = false;                                           // tau* < 2
    }

    if (ok) {
      for (int it = 0; it < CAP + 2; ++it) {
        float ps = 0.f; int pc = 0;
        for (int i = lane; i < n; i += WAVE) {
          float a = s_act[wv][i];
          bool  g = a > tau;
          ps += g ? a : 0.f;
          pc += g ? 1 : 0;
        }
        ps = wsum(ps);  pc = wsumi(pc);
        tau = (ps - Z_LVL) / (float)pc;
        if (pc == prev) break;                              // stable -> exact
        prev = pc;
      }
    }
  }

  if (!ok) {
    // ---- fallback (adversarial data only): full Michelot via cached reads ----
    tau  = (sAll - Z_LVL) / (float)N_COLS;
    prev = N_COLS;
    for (int it = 0; it < 100; ++it) {
      float ps = 0.f; int pc = 0;
      for (int k = 0; k < V4; ++k) {
        f32x4 t = xin[lane + k * WAVE];
#pragma unroll
        for (int j = 0; j < 4; ++j) {
          bool g = t[j] > tau;
          ps += g ? t[j] : 0.f;
          pc += g ? 1 : 0;
        }
      }
      ps = wsum(ps);  pc = wsumi(pc);
      tau = (ps - Z_LVL) / (float)pc;
      if (pc == prev) break;
      prev = pc;
    }
  }

  // ---- phase 2: re-read row (cache-hot) -> compute -> NT-store wp & wc ----
  f32x4* __restrict__ wpo = reinterpret_cast<f32x4*>(wp + base);
  f32x4* __restrict__ wco = reinterpret_cast<f32x4*>(wc + base);
#pragma unroll 4
  for (int k = 0; k < V4; ++k) {
    f32x4 t = xin[lane + k * WAVE];        // L2/L3 hit: read ~1us ago
    f32x4 pv, cv;
#pragma unroll
    for (int j = 0; j < 4; ++j) {
      pv[j] = fmaxf(t[j] - tau, 0.f);
      cv[j] = t[j] - pv[j];
    }
    __builtin_nontemporal_store(pv, &wpo[lane + k * WAVE]);
    __builtin_nontemporal_store(cv, &wco[lane + k * WAVE]);
  }
}

extern "C" void kernel_launch(void* const* d_in, const int* in_sizes, int n_in,
                              void* d_out, int out_size, void* d_ws, size_t ws_size,
                              hipStream_t stream) {
  const float* x = (const float*)d_in[0];
  const int rows = in_sizes[0] / N_COLS;

  float* wp = (float*)d_out;
  float* wc = wp + (size_t)rows * N_COLS;

  const int nblk = (rows + WPB - 1) / WPB;
  simplex_fused2<<<nblk, BLOCK, 0, stream>>>(x, wp, wc, rows);
}

// Round 11
// 102.671 us; speedup vs baseline: 1.3212x; 1.0775x over previous
//
#include <hip/hip_runtime.h>

// Simplex projection along last dim (n = 12288), rows = 4096, fp32.
// wp = max(x - tau, 0), wc = x - wp, tau solves sum(max(x-tau,0)) = Z.
//
// LDS-STAGED SINGLE PASS, ONE ROW PER BLOCK (512 thr / 8 waves), ONE BARRIER:
//   phase 1 (pure-read stream): x -> regs -> ds_write row into LDS (48 KB),
//     accumulate sAll, ballot-append the ~280 elements > 2.0 into per-wave
//     LDS segments (SGPR counter + popc offsets, no atomics).
//   __syncthreads()  [the only barrier; vmcnt(0) drain harmless -- loads done]
//   solve: every wave redundantly reads all 8 segments + counts, computes
//     bootstrap stats (t in {2,3}; g(t)=S_t-t*C_t >= Z  <=>  t <= tau*),
//     then Michelot on the segments (~4 iters, shuffle reduces) -> identical
//     tau in all waves, no broadcast. Fallback: full-row Michelot FROM LDS.
//   phase 2 (pure-write stream): read row back from LDS (contiguous b128,
//     conflict-free), compute wp/wc, NT-store both.
// Global traffic: exactly 192R + 384W MB -- no L3 re-read dependence (R10's
// 110.6us carried ~120MB of re-read leak to HBM). LDS adds 96 KB/row at
// 69 TB/s aggregate (~3% of the time budget, fully hidden).
// Occupancy: 52 KB LDS -> 3 blocks/CU = 24 waves/CU at ~40 VGPR; 4096 blocks
// retire over ~5 generations -> reads of fresh blocks overlap writes of
// finishing blocks for the whole kernel (no chip-wide phase lock).
//
// Michelot from subset start: if A0 = {x > t} with t <= tau*, every iterate
// tau_k in [t, tau*], active sets stay within A0, counts shrink to the fixed
// point; count-stable <=> exact. Validity g(t) >= Z <=> tau0 >= t.

constexpr int   N_COLS = 12288;
constexpr int   BLOCK  = 512;
constexpr int   NWAVE  = BLOCK / 64;              // 8
constexpr int   V4     = N_COLS / (BLOCK * 4);    // 6 f32x4 per thread
constexpr float Z_LVL  = 1.0f;
constexpr int   CAP_W  = 128;                     // per-wave list cap (mean 35, sd 6)
constexpr float T2     = 2.0f;
constexpr float T3     = 3.0f;

typedef float f32x4 __attribute__((ext_vector_type(4)));

struct SharedMem {
  float row[N_COLS];          // 48 KB staged row
  float seg[NWAVE][CAP_W];    // per-wave >2.0 value lists
  int   nw[NWAVE];            // per-wave list lengths
  float sAllw[NWAVE];         // per-wave full sums
};

__device__ __forceinline__ float wsum(float v) {
#pragma unroll
  for (int off = 32; off >= 1; off >>= 1) v += __shfl_xor(v, off, 64);
  return v;
}
__device__ __forceinline__ int wsumi(int v) {
#pragma unroll
  for (int off = 32; off >= 1; off >>= 1) v += __shfl_xor(v, off, 64);
  return v;
}

__global__ __launch_bounds__(BLOCK) void simplex_lds(
    const float* __restrict__ x, float* __restrict__ wp, float* __restrict__ wc,
    int rows) {

  __shared__ SharedMem sh;

  const int tid  = threadIdx.x;
  const int lane = tid & 63;
  const int wv   = tid >> 6;
  const int row  = blockIdx.x;
  if (row >= rows) return;

  const size_t base = (size_t)row * N_COLS;
  const f32x4* __restrict__ xin = reinterpret_cast<const f32x4*>(x + base);
  f32x4* __restrict__ rowv = reinterpret_cast<f32x4*>(sh.row);

  const unsigned long long lt_mask = (lane == 0) ? 0ull : (~0ull >> (64 - lane));

  // ---- phase 1: pure-read stream -> LDS row + stats + per-wave list ----
  float sAll = 0.f;
  int   n    = 0;          // wave-uniform (SGPR) segment length
  bool  ovf  = false;

#pragma unroll
  for (int k = 0; k < V4; ++k) {
    f32x4 t = xin[tid + k * BLOCK];
    rowv[tid + k * BLOCK] = t;
#pragma unroll
    for (int j = 0; j < 4; ++j) {
      float e = t[j];
      sAll += e;
      unsigned long long m = __ballot(e > T2);
      if (m) {                              // wave-uniform, rarely taken
        int c = (int)__popcll(m);
        if (n + c <= CAP_W) {
          if (e > T2) sh.seg[wv][n + (int)__popcll(m & lt_mask)] = e;
        } else {
          ovf = true;
        }
        n += c;
      }
    }
  }
  sAll = wsum(sAll);
  if (lane == 0) { sh.nw[wv] = ovf ? -1 : n; sh.sAllw[wv] = sAll; }

  __syncthreads();   // the only barrier: row + segments + counts visible

  // ---- solve tau (every wave redundantly -> identical result) ----
  float tau  = 0.f;
  int   prev = 0;
  bool  ok   = true;
  int   ntot = 0;
  float sAllTot = 0.f;
#pragma unroll
  for (int w = 0; w < NWAVE; ++w) {
    int nwv = sh.nw[w];
    if (nwv < 0) ok = false;
    ntot += nwv;
    sAllTot += sh.sAllw[w];
  }
  ok = ok && (ntot > 0);

  if (ok) {
    // stats from the segments
    float s2 = 0.f, s3 = 0.f;
    int   c3 = 0;
#pragma unroll
    for (int w = 0; w < NWAVE; ++w) {
      const int nwv = sh.nw[w];
      for (int i = lane; i < nwv; i += 64) {
        float a = sh.seg[w][i];
        s2 += a;
        bool g3 = a > T3;
        s3 += g3 ? a : 0.f;
        c3 += g3 ? 1 : 0;
      }
    }
    s2 = wsum(s2);  s3 = wsum(s3);  c3 = wsumi(c3);
    const int c2 = ntot;

    if (c3 > 0 && (s3 - 3.f * (float)c3) >= Z_LVL + 0.01f) {
      tau = (s3 - Z_LVL) / (float)c3;  prev = c3;           // tau >= 3
    } else if ((s2 - 2.f * (float)c2) >= Z_LVL + 0.01f) {
      tau = (s2 - Z_LVL) / (float)c2;  prev = c2;           // tau >= 2
    } else {
      ok = false;                                           // tau* < 2
    }

    if (ok) {
      for (int it = 0; it < 2 * CAP_W; ++it) {
        float ps = 0.f; int pc = 0;
#pragma unroll
        for (int w = 0; w < NWAVE; ++w) {
          const int nwv = sh.nw[w];
          for (int i = lane; i < nwv; i += 64) {
            float a = sh.seg[w][i];
            bool  g = a > tau;
            ps += g ? a : 0.f;
            pc += g ? 1 : 0;
          }
        }
        ps = wsum(ps);  pc = wsumi(pc);
        tau = (ps - Z_LVL) / (float)pc;
        if (pc == prev) break;                              // stable -> exact
        prev = pc;
      }
    }
  }

  if (!ok) {
    // ---- fallback (adversarial only): full-row Michelot FROM LDS ----
    tau  = (sAllTot - Z_LVL) / (float)N_COLS;
    prev = N_COLS;
    for (int it = 0; it < 100; ++it) {
      float ps = 0.f; int pc = 0;
      for (int i = lane; i < N_COLS; i += 64) {
        float a = sh.row[i];
        bool  g = a > tau;
        ps += g ? a : 0.f;
        pc += g ? 1 : 0;
      }
      ps = wsum(ps);  pc = wsumi(pc);
      tau = (ps - Z_LVL) / (float)pc;
      if (pc == prev) break;
      prev = pc;
    }
  }

  // ---- phase 2: LDS row -> compute -> NT-store wp & wc ----
  f32x4* __restrict__ wpo = reinterpret_cast<f32x4*>(wp + base);
  f32x4* __restrict__ wco = reinterpret_cast<f32x4*>(wc + base);
#pragma unroll
  for (int k = 0; k < V4; ++k) {
    f32x4 t = rowv[tid + k * BLOCK];
    f32x4 pv, cv;
#pragma unroll
    for (int j = 0; j < 4; ++j) {
      pv[j] = fmaxf(t[j] - tau, 0.f);
      cv[j] = t[j] - pv[j];
    }
    __builtin_nontemporal_store(pv, &wpo[tid + k * BLOCK]);
    __builtin_nontemporal_store(cv, &wco[tid + k * BLOCK]);
  }
}

extern "C" void kernel_launch(void* const* d_in, const int* in_sizes, int n_in,
                              void* d_out, int out_size, void* d_ws, size_t ws_size,
                              hipStream_t stream) {
  const float* x = (const float*)d_in[0];
  const int rows = in_sizes[0] / N_COLS;

  float* wp = (float*)d_out;
  float* wc = wp + (size_t)rows * N_COLS;

  simplex_lds<<<rows, BLOCK, 0, stream>>>(x, wp, wc, rows);
}